// Round 19
// baseline (258.736 us; speedup 1.0000x reference)
//
#include <hip/hip_runtime.h>
#include <hip/hip_bf16.h>
#include <stdint.h>

typedef float f32x4 __attribute__((ext_vector_type(4)));
typedef short s16x8 __attribute__((ext_vector_type(8)));
typedef short s16x4 __attribute__((ext_vector_type(4)));
typedef unsigned short u16x2 __attribute__((ext_vector_type(2)));
typedef unsigned short u16x4 __attribute__((ext_vector_type(4)));

#define AS1 __attribute__((address_space(1)))
#define AS3 __attribute__((address_space(3)))

static constexpr int T_    = 2048;
static constexpr int DIM_  = 3072;
static constexpr int HQ_   = 32;
static constexpr int HKV_  = 8;
static constexpr int HD_   = 128;
static constexpr int S_    = 4096;
static constexpr int NQKV_ = HQ_ * HD_ + 2 * HKV_ * HD_;   // 6144

__device__ __forceinline__ unsigned short f2b(float f) {
  return __builtin_bit_cast(unsigned short, __float2bfloat16(f));
}
__device__ __forceinline__ float b2f(unsigned short u) {
  return __bfloat162float(__builtin_bit_cast(__hip_bfloat16, u));
}
__device__ __forceinline__ float exp2a(float x) {      // exact v_exp_f32: 2^x
  float r; asm("v_exp_f32 %0, %1" : "=v"(r) : "v"(x)); return r;
}

__device__ __forceinline__ void gld_lds16(const void* g, void* l) {
  __builtin_amdgcn_global_load_lds((AS1 unsigned int*)(uintptr_t)g,
                                   (AS3 unsigned int*)l, 16, 0, 0);
}

#define FENCE() asm volatile("" ::: "memory")
#define BAR()   do { FENCE(); __builtin_amdgcn_s_barrier(); FENCE(); } while (0)
#define WAIT_VM(n)   asm volatile("s_waitcnt vmcnt(" #n ")" ::: "memory")
#define WAIT_LGKM(n) asm volatile("s_waitcnt lgkmcnt(" #n ")" ::: "memory")
#define SCHEDB()     __builtin_amdgcn_sched_barrier(0)

// ---------------- merged convert: x | wq | wk | wv -> bf16 ------------------
__global__ __launch_bounds__(256)
void k_cvtA(const float* __restrict__ x,  const float* __restrict__ wq,
            const float* __restrict__ wk, const float* __restrict__ wv,
            unsigned short* __restrict__ xb, unsigned short* __restrict__ wqkv) {
  int idx = blockIdx.x * 256 + threadIdx.x;            // float4 units
  if (idx < 1572864) {
    float4 v = reinterpret_cast<const float4*>(x)[idx];
    u16x4 o;
    o.x = f2b(v.x); o.y = f2b(v.y); o.z = f2b(v.z); o.w = f2b(v.w);
    reinterpret_cast<u16x4*>(xb)[idx] = o;
  } else {
    int j = idx - 1572864;                             // 0..4718591
    const float* src; int s;
    if (j < 3145728)      { src = wq; s = j; }
    else if (j < 3932160) { src = wk; s = j - 3145728; }
    else                  { src = wv; s = j - 3932160; }
    float4 v = reinterpret_cast<const float4*>(src)[s];
    u16x4 o;
    o.x = f2b(v.x); o.y = f2b(v.y); o.z = f2b(v.z); o.w = f2b(v.w);
    reinterpret_cast<u16x4*>(wqkv)[j] = o;
  }
}

// ---------------- BMT x 192 8-wave NT GEMM, bf16 B (verified round 12) ------
template<int BMT, bool OUT_BF16>
__global__ __launch_bounds__(512, 4)
void k_gemm192(const unsigned short* __restrict__ A,
               const unsigned short* __restrict__ B,
               void* __restrict__ Cout, int N, int K, int KT,
               int nbn, int xcdq) {
  constexpr int AROWS  = BMT / 64;
  constexpr int AFRAG  = BMT / 32;
  constexpr int LDSBUF = BMT * 128 + 24576;
  __shared__ char lds[2 * LDSBUF];
  const int bid = blockIdx.x;
  const int swz = (bid & 7) * xcdq + (bid >> 3);       // bijective: nwg % 8 == 0
  const int bm  = swz / nbn, bn = swz % nbn;
  const int tid = threadIdx.x, lane = tid & 63, wid = tid >> 6;
  const int wm  = wid >> 2, wn = wid & 3;              // 2 x 4
  const int r16 = lane & 15, q4 = lane >> 4;

  const unsigned short* Ag = A + (size_t)(bm * BMT) * K;
  const unsigned short* Bg = B + (size_t)(bn * 192) * K;

  const int srow = tid >> 3;                            // 0..63
  const int scol = ((tid & 7) ^ (srow & 7)) * 8;        // pre-swizzled src col

  f32x4 acc[AFRAG][3] = {};
  s16x8 af[AFRAG][2];

  auto stageA = [&](int c, int r, int t) {
    gld_lds16(Ag + (size_t)(r * 64 + srow) * K + t * 64 + scol,
              lds + c * LDSBUF + r * 8192 + tid * 16);
  };
  auto stageB = [&](int c, int r, int t) {
    gld_lds16(Bg + (size_t)(r * 64 + srow) * K + t * 64 + scol,
              lds + c * LDSBUF + BMT * 128 + r * 8192 + tid * 16);
  };
  auto readA = [&](int c) {
    #pragma unroll
    for (int i = 0; i < AFRAG; ++i) {
      const int arow = wm * (BMT / 2) + i * 16 + r16;
      #pragma unroll
      for (int kk = 0; kk < 2; ++kk)
        af[i][kk] = *(const s16x8*)(lds + c * LDSBUF + arow * 128 +
                                    (((kk * 4 + q4) ^ (arow & 7)) << 4));
    }
  };
  auto readB = [&](s16x8 (&dst)[2], int c, int j) {
    const int brow = wn * 48 + j * 16 + r16;
    #pragma unroll
    for (int kk = 0; kk < 2; ++kk)
      dst[kk] = *(const s16x8*)(lds + c * LDSBUF + BMT * 128 + brow * 128 +
                                (((kk * 4 + q4) ^ (brow & 7)) << 4));
  };

#define MFMA8(BF, J)                                                           \
  __builtin_amdgcn_s_setprio(1);                                               \
  _Pragma("unroll")                                                            \
  for (int i_ = 0; i_ < AFRAG; ++i_) {                                         \
    _Pragma("unroll")                                                          \
    for (int kk_ = 0; kk_ < 2; ++kk_)                                          \
      acc[i_][J] = __builtin_amdgcn_mfma_f32_16x16x32_bf16(                    \
          af[i_][kk_], BF[kk_], acc[i_][J], 0, 0, 0);                          \
  }                                                                            \
  __builtin_amdgcn_s_setprio(0);

  #pragma unroll
  for (int r = 0; r < AROWS; ++r) stageA(0, r, 0);
  stageB(0, 0, 0); stageB(0, 1, 0); stageB(0, 2, 0);
  WAIT_VM(0);
  BAR();

  for (int t = 0; t < KT; ++t) {
    const int c = t & 1;
    const bool hn = (t + 1 < KT);
    s16x8 bf0[2], bf1[2], bf2[2];
    readA(c);
    readB(bf0, c, 0);
    if (hn) {
      #pragma unroll
      for (int r = 0; r < AROWS; ++r) stageA(c ^ 1, r, t + 1);
      stageB(c ^ 1, 0, t + 1); stageB(c ^ 1, 1, t + 1); stageB(c ^ 1, 2, t + 1);
    }
    readB(bf1, c, 1);
    WAIT_LGKM(2); SCHEDB();
    MFMA8(bf0, 0);
    readB(bf2, c, 2);
    WAIT_LGKM(2); SCHEDB();
    MFMA8(bf1, 1);
    WAIT_LGKM(0); SCHEDB();
    MFMA8(bf2, 2);
    if (hn) WAIT_VM(0);
    BAR();
  }
#undef MFMA8

  #pragma unroll
  for (int i = 0; i < AFRAG; ++i) {
    const int row = bm * BMT + wm * (BMT / 2) + i * 16 + q4 * 4;
    #pragma unroll
    for (int j = 0; j < 3; ++j) {
      const int col = bn * 192 + wn * 48 + j * 16 + r16;
      if constexpr (OUT_BF16) {
        unsigned short* C = (unsigned short*)Cout;
        #pragma unroll
        for (int rr = 0; rr < 4; ++rr)
          C[(size_t)(row + rr) * N + col] = f2b(acc[i][j][rr]);
      } else {
        float* C = (float*)Cout;
        #pragma unroll
        for (int rr = 0; rr < 4; ++rr)
          C[(size_t)(row + rr) * N + col] = acc[i][j][rr];
      }
    }
  }
}

// ---------------- merged prep: wo-cvt | ropeK | V-transpose | prefix --------
__global__ __launch_bounds__(256)
void k_prep(const unsigned short* __restrict__ qkv,
            const float* __restrict__ fc, const float* __restrict__ fs,
            const float* __restrict__ kc, const float* __restrict__ vc,
            const float* __restrict__ wo, unsigned short* __restrict__ wo_b,
            unsigned short* __restrict__ Kall,
            unsigned short* __restrict__ VT, const int* __restrict__ ipos) {
  __shared__ unsigned short lds[64][136];
  const int b = blockIdx.x, tid = threadIdx.x;

  if (b < 12288) {                             // ---- wo f32 -> bf16
    int idx = b * 256 + tid;                   // f4 units, 3145728 total
    float4 v = reinterpret_cast<const float4*>(wo)[idx];
    u16x4 o;
    o.x = f2b(v.x); o.y = f2b(v.y); o.z = f2b(v.z); o.w = f2b(v.w);
    reinterpret_cast<u16x4*>(wo_b)[idx] = o;

  } else if (b < 13312) {                      // ---- RoPE K -> Kall
    int idx = (b - 12288) * 256 + tid;
    int t   = idx >> 7;
    int rem = idx & 127;
    int hk  = rem >> 4;
    int c8  = (rem & 15) << 3;
    int sp  = ipos[0];
    s16x8 xv = *(const s16x8*)(qkv + (size_t)t * NQKV_ + HQ_ * HD_ + hk * HD_ + c8);
    float4 ca = *(const float4*)(fc + t * HD_ + c8);
    float4 cb = *(const float4*)(fc + t * HD_ + c8 + 4);
    float4 sa = *(const float4*)(fs + t * HD_ + c8);
    float4 sb = *(const float4*)(fs + t * HD_ + c8 + 4);
    float cc[8] = {ca.x, ca.y, ca.z, ca.w, cb.x, cb.y, cb.z, cb.w};
    float ss[8] = {sa.x, sa.y, sa.z, sa.w, sb.x, sb.y, sb.z, sb.w};
    s16x8 o;
    #pragma unroll
    for (int i = 0; i < 4; ++i) {
      float x0 = b2f((unsigned short)xv[2 * i]);
      float x1 = b2f((unsigned short)xv[2 * i + 1]);
      o[2 * i]     = (short)f2b(x0 * cc[2 * i]     - x1 * ss[2 * i]);
      o[2 * i + 1] = (short)f2b(x1 * cc[2 * i + 1] + x0 * ss[2 * i + 1]);
    }
    *(s16x8*)(Kall + ((size_t)hk * S_ + sp + t) * HD_ + c8) = o;

  } else if (b < 13568) {                      // ---- V transpose -> VT
    int bb = b - 13312;
    int hk = bb >> 5;
    int tt = bb & 31;
    int sp = ipos[0];
    #pragma unroll
    for (int p = 0; p < 4; ++p) {
      int e   = p * 256 + tid;
      int tr  = e >> 4;
      int col = (e & 15) << 3;
      *reinterpret_cast<s16x8*>(&lds[tr][col]) =
          *reinterpret_cast<const s16x8*>(&qkv[(size_t)(tt * 64 + tr) * NQKV_ +
                                               (HQ_ + HKV_) * HD_ + hk * HD_ + col]);
    }
    __syncthreads();
    #pragma unroll
    for (int p = 0; p < 32; ++p) {
      int e = p * 256 + tid;
      int d = e >> 6;
      int t = e & 63;
      VT[((size_t)hk * HD_ + d) * S_ + sp + tt * 64 + t] = lds[t][d];
    }

  } else {                                     // ---- cache prefix (s < sp)
    int sp = ipos[0];
    int total = sp * HKV_ * HD_;
    for (int idx = (b - 13568) * 256 + tid; idx < total; idx += 256 * 256) {
      int s   = idx >> 10;
      int rem = idx & 1023;
      int hk  = rem >> 7;
      int d   = rem & 127;
      Kall[((size_t)hk * S_ + s) * HD_ + d] = f2b(kc[((size_t)s * HKV_ + hk) * HD_ + d]);
      VT[((size_t)hk * HD_ + d) * S_ + s]   = f2b(vc[((size_t)s * HKV_ + hk) * HD_ + d]);
    }
  }
}

// ---------------- flash attention v8: single-buffered K, 3 blocks/CU --------
// K consumed early (QK^T), V late (PV): K needs no dbuf. Per tile:
// {vmcnt(0)+BAR1 publish K[j],V[j]} -> QK^T(Kbuf) -> BAR2 (Kbuf free) ->
// stageK(j+1)+stageV(j+1,c^1) -> softmax+PV(V[c]). LDS 48 KiB -> 3 blocks/CU.
// Barrier count/tile unchanged (2). Math identical to verified v3+RoPE-Q.
__global__ __launch_bounds__(256, 3)
void k_attn(const unsigned short* __restrict__ qkv,
            const float* __restrict__ fc, const float* __restrict__ fs,
            const unsigned short* __restrict__ Kall,
            const unsigned short* __restrict__ VT,
            unsigned short* __restrict__ Y,
            const int* __restrict__ ipos) {
  constexpr int QB = 64, KB = 64;
  __shared__ char lds[49152];                 // K 16K | V[2] 2x16K
  const int bid  = blockIdx.x;
  const int hk   = bid & 7;
  const int j2   = bid >> 3;                  // 0..127
  const int h    = hk * 4 + (j2 & 3);
  const int qt   = 31 - (j2 >> 2);            // LPT: longest first
  const int tid  = threadIdx.x, lane = tid & 63, wave = tid >> 6;
  const int r16  = lane & 15, q4 = lane >> 4;
  const int vx   = r16 & 7;                   // row-XOR for all LDS reads
  const float NEG_INF = -__builtin_inff();
  const float MINIT   = -1.0e30f;

  const int sp = ipos[0];
  const int qbase = qt * QB + wave * 16;
  const unsigned short* Kbase = Kall + (size_t)hk * S_ * HD_;
  const unsigned short* Vbase = VT + (size_t)hk * HD_ * S_;

  // Q fragments straight from qkv + in-register RoPE (pairs are lane-local)
  s16x8 qf[4];
  {
    const int tq = qbase + r16;
    const unsigned short* qp = qkv + (size_t)tq * NQKV_ + h * HD_;
    const float* fcb = fc + tq * HD_;
    const float* fsb = fs + tq * HD_;
    #pragma unroll
    for (int ki = 0; ki < 4; ++ki) {
      const int d0 = ki * 32 + q4 * 8;
      s16x8 xv = *reinterpret_cast<const s16x8*>(qp + d0);
      float4 ca = *(const float4*)(fcb + d0);
      float4 cb = *(const float4*)(fcb + d0 + 4);
      float4 sa = *(const float4*)(fsb + d0);
      float4 sb = *(const float4*)(fsb + d0 + 4);
      float cc[8] = {ca.x, ca.y, ca.z, ca.w, cb.x, cb.y, cb.z, cb.w};
      float ss[8] = {sa.x, sa.y, sa.z, sa.w, sb.x, sb.y, sb.z, sb.w};
      #pragma unroll
      for (int i = 0; i < 4; ++i) {
        float x0 = b2f((unsigned short)xv[2 * i]);
        float x1 = b2f((unsigned short)xv[2 * i + 1]);
        qf[ki][2 * i]     = (short)f2b(x0 * cc[2 * i]     - x1 * ss[2 * i]);
        qf[ki][2 * i + 1] = (short)f2b(x1 * cc[2 * i + 1] + x0 * ss[2 * i + 1]);
      }
    }
  }
  SCHEDB(); WAIT_VM(0); SCHEDB();             // drain Q/freq loads

  auto stageK = [&](int jt) {                 // 4 gld_lds -> single K buffer
    #pragma unroll
    for (int p = 0; p < 4; ++p) {
      int e  = p * 256 + tid;
      int kr = e >> 4;
      int ks = (e & 15) ^ (kr & 7);
      gld_lds16(Kbase + (size_t)(jt * KB + kr) * HD_ + ks * 8, lds + e * 16);
    }
  };
  auto stageV = [&](int c, int jt) {          // 4 gld_lds -> V dbuf[c]
    #pragma unroll
    for (int p = 0; p < 4; ++p) {
      int e  = p * 256 + tid;
      int vd = e >> 3;
      int vs = (e & 7) ^ (vd & 7);
      gld_lds16(Vbase + (size_t)vd * S_ + jt * KB + vs * 8,
                lds + 16384 + c * 16384 + e * 16);
    }
  };

  f32x4 o[8] = {};
  float m = MINIT, l = 0.f;
  const int qpos = sp + qbase + r16;
  const int qpos_wave_max = sp + qbase + 15;
  int jmax = (sp + qt * QB + QB - 1) >> 6;
  if (jmax > S_ / KB - 1) jmax = S_ / KB - 1;
  const float scale2 = 0.12751744416312068f;  // 1/sqrt(128) * log2(e)

  stageK(0); stageV(0, 0);                    // prologue: tile 0 in flight (8)

  for (int j = 0; j <= jmax; ++j) {
    const int c = j & 1;
    WAIT_VM(0);                               // my K[j]+V[j] loads landed
    BAR();                                    // BAR1: tile j published

    const bool active = (j * KB <= qpos_wave_max);
    f32x4 sfr[4];
    if (active) {
      __builtin_amdgcn_s_setprio(1);
      #pragma unroll
      for (int fn = 0; fn < 4; ++fn) {
        sfr[fn] = f32x4{0.f, 0.f, 0.f, 0.f};
        #pragma unroll
        for (int ki = 0; ki < 4; ++ki) {
          s16x8 kf = *(const s16x8*)(lds + (fn * 16 + r16) * 256 +
                                     (((ki * 4 + q4) ^ vx) << 4));
          sfr[fn] = __builtin_amdgcn_mfma_f32_16x16x32_bf16(kf, qf[ki], sfr[fn], 0, 0, 0);
        }
      }
      __builtin_amdgcn_s_setprio(0);
    }
    WAIT_LGKM(0);                             // my Kbuf reads complete
    BAR();                                    // BAR2: Kbuf free for overwrite

    if (j < jmax) { stageK(j + 1); stageV(c ^ 1, j + 1); }

    if (active) {
      const char* vb = lds + 16384 + c * 16384;
      float p[16];
      const bool needMask = (j * KB + KB - 1) > (sp + qbase);   // wave-uniform
      if (needMask) {
        const int kbp = j * KB + q4 * 4;
        #pragma unroll
        for (int fn = 0; fn < 4; ++fn)
          #pragma unroll
          for (int r = 0; r < 4; ++r)
            p[fn * 4 + r] = (kbp + fn * 16 + r <= qpos) ? sfr[fn][r] * scale2 : NEG_INF;
      } else {
        #pragma unroll
        for (int fn = 0; fn < 4; ++fn)
          #pragma unroll
          for (int r = 0; r < 4; ++r)
            p[fn * 4 + r] = sfr[fn][r] * scale2;
      }
      float t0 = fmaxf(p[0], p[1]),  t1 = fmaxf(p[2], p[3]);
      float t2 = fmaxf(p[4], p[5]),  t3 = fmaxf(p[6], p[7]);
      float t4 = fmaxf(p[8], p[9]),  t5 = fmaxf(p[10], p[11]);
      float t6 = fmaxf(p[12], p[13]), t7 = fmaxf(p[14], p[15]);
      float pmax = fmaxf(fmaxf(fmaxf(t0, t1), fmaxf(t2, t3)),
                         fmaxf(fmaxf(t4, t5), fmaxf(t6, t7)));
      pmax = fmaxf(pmax, __shfl_xor(pmax, 16));
      pmax = fmaxf(pmax, __shfl_xor(pmax, 32));
      if (!__all(pmax <= m + 8.0f)) {                 // defer-max (log2 units)
        float mn = fmaxf(m, pmax);
        float alpha = exp2a(m - mn);
        m = mn; l *= alpha;
        #pragma unroll
        for (int r = 0; r < 4; ++r) {
          float aq = __shfl(alpha, q4 * 4 + r);
          #pragma unroll
          for (int db = 0; db < 8; ++db) o[db][r] *= aq;
        }
      }
      float rs = 0.f;
      #pragma unroll
      for (int i = 0; i < 16; ++i) { p[i] = exp2a(p[i] - m); rs += p[i]; }
      rs += __shfl_xor(rs, 16); rs += __shfl_xor(rs, 32);
      l += rs;
      s16x8 pf[2];
      #pragma unroll
      for (int w = 0; w < 2; ++w)
        #pragma unroll
        for (int i = 0; i < 8; ++i)
          pf[w][i] = (short)f2b(p[w * 8 + i]);
      const int voff = (q4 & 1) * 8;
      const int sbase = q4 >> 1;
      __builtin_amdgcn_s_setprio(1);
      #pragma unroll
      for (int w = 0; w < 2; ++w) {
        #pragma unroll
        for (int db = 0; db < 8; ++db) {
          const char* vr = vb + (db * 16 + r16) * 128 + voff;
          s16x4 va  = *(const s16x4*)(vr + (((w * 4 + sbase) ^ vx) << 4));
          s16x4 vb2 = *(const s16x4*)(vr + (((w * 4 + 2 + sbase) ^ vx) << 4));
          s16x8 vf = __builtin_shufflevector(va, vb2, 0, 1, 2, 3, 4, 5, 6, 7);
          o[db] = __builtin_amdgcn_mfma_f32_16x16x32_bf16(pf[w], vf, o[db], 0, 0, 0);
        }
      }
      __builtin_amdgcn_s_setprio(0);
    }
    // loop wraps: vmcnt(0)+BAR1 orders my V[c] reads before next overwrite
  }

  float rcpl = 1.0f / l;
  float rlq[4];
  #pragma unroll
  for (int r = 0; r < 4; ++r) rlq[r] = __shfl(rcpl, q4 * 4 + r);
  #pragma unroll
  for (int db = 0; db < 8; ++db)
    #pragma unroll
    for (int r = 0; r < 4; ++r) {
      int t = qt * QB + wave * 16 + q4 * 4 + r;
      int d = db * 16 + r16;
      Y[(size_t)t * (HQ_ * HD_) + h * HD_ + d] = f2b(o[db][r] * rlq[r]);
    }
}

// ---------------------------------------------------------------------------
extern "C" void kernel_launch(void* const* d_in, const int* in_sizes, int n_in,
                              void* d_out, int out_size, void* d_ws, size_t ws_size,
                              hipStream_t stream) {
  const float* x  = (const float*)d_in[0];
  const float* wq = (const float*)d_in[1];
  const float* wk = (const float*)d_in[2];
  const float* wv = (const float*)d_in[3];
  const float* wo = (const float*)d_in[4];
  const float* fc = (const float*)d_in[5];
  const float* fs = (const float*)d_in[6];
  const float* kc = (const float*)d_in[7];
  const float* vc = (const float*)d_in[8];
  const int* ipos = (const int*)d_in[9];

  char* ws = (char*)d_ws;
  unsigned short* xb   = (unsigned short*)(ws);                 // [0, 12.58 MB)
  unsigned short* wqkv = (unsigned short*)(ws + 12582912);      // [12.58, 50.33)
  unsigned short* qkv  = (unsigned short*)(ws + 50331648);      // [50.33, 75.50)
  unsigned short* y    = (unsigned short*)(ws + 75497472);      // [75.50, 92.27) no alias
  unsigned short* Kall = (unsigned short*)(ws + 92274688);      // [92.27, 100.66)
  unsigned short* VT   = (unsigned short*)(ws + 100663296);     // [100.66, 109.05)
  unsigned short* wo_b = (unsigned short*)(ws);                 // reuse region 0 after QKV GEMM

  // converts: x + wq + wk + wv, one launch
  k_cvtA<<<24576, 256, 0, stream>>>(x, wq, wk, wv, xb, wqkv);

  // fused QKV projection: qkv[2048][6144] = xb @ wqkv^T (512 blocks = 2/CU)
  k_gemm192<128, true><<<512, 512, 0, stream>>>(xb, wqkv, qkv, NQKV_, DIM_, 48, 32, 64);

  // merged wo-cvt / RoPE-K / V-transpose / prefix (region 0 dead now)
  k_prep<<<13824, 256, 0, stream>>>(qkv, fc, fs, kc, vc, wo, wo_b, Kall, VT, ipos);

  // attention -> y: v8 single-K-buffer, 3 blocks/CU, 1024 blocks
  k_attn<<<1024, 256, 0, stream>>>(qkv, fc, fs, Kall, VT, y, ipos);

  // output projection: out[2048][3072] = y @ wo_b^T, f32 direct (BM=64, 2/CU)
  k_gemm192<64, false><<<512, 512, 0, stream>>>(y, wo_b, d_out, DIM_, HQ_ * HD_, 64, 16, 64);
}

// Round 20
// 248.023 us; speedup vs baseline: 1.0432x; 1.0432x over previous
//
#include <hip/hip_runtime.h>
#include <hip/hip_bf16.h>
#include <stdint.h>

typedef float f32x4 __attribute__((ext_vector_type(4)));
typedef short s16x8 __attribute__((ext_vector_type(8)));
typedef short s16x4 __attribute__((ext_vector_type(4)));
typedef unsigned short u16x2 __attribute__((ext_vector_type(2)));
typedef unsigned short u16x4 __attribute__((ext_vector_type(4)));

#define AS1 __attribute__((address_space(1)))
#define AS3 __attribute__((address_space(3)))

static constexpr int T_    = 2048;
static constexpr int DIM_  = 3072;
static constexpr int HQ_   = 32;
static constexpr int HKV_  = 8;
static constexpr int HD_   = 128;
static constexpr int S_    = 4096;
static constexpr int NQKV_ = HQ_ * HD_ + 2 * HKV_ * HD_;   // 6144

__device__ __forceinline__ unsigned short f2b(float f) {
  return __builtin_bit_cast(unsigned short, __float2bfloat16(f));
}
__device__ __forceinline__ float b2f(unsigned short u) {
  return __bfloat162float(__builtin_bit_cast(__hip_bfloat16, u));
}
__device__ __forceinline__ float exp2a(float x) {      // exact v_exp_f32: 2^x
  float r; asm("v_exp_f32 %0, %1" : "=v"(r) : "v"(x)); return r;
}

__device__ __forceinline__ void gld_lds16(const void* g, void* l) {
  __builtin_amdgcn_global_load_lds((AS1 unsigned int*)(uintptr_t)g,
                                   (AS3 unsigned int*)l, 16, 0, 0);
}

#define FENCE() asm volatile("" ::: "memory")
#define BAR()   do { FENCE(); __builtin_amdgcn_s_barrier(); FENCE(); } while (0)
#define WAIT_VM(n)   asm volatile("s_waitcnt vmcnt(" #n ")" ::: "memory")
#define WAIT_LGKM(n) asm volatile("s_waitcnt lgkmcnt(" #n ")" ::: "memory")
#define SCHEDB()     __builtin_amdgcn_sched_barrier(0)

// ---------------- merged convert: x | wq | wk | wv -> bf16 ------------------
__global__ __launch_bounds__(256)
void k_cvtA(const float* __restrict__ x,  const float* __restrict__ wq,
            const float* __restrict__ wk, const float* __restrict__ wv,
            unsigned short* __restrict__ xb, unsigned short* __restrict__ wqkv) {
  int idx = blockIdx.x * 256 + threadIdx.x;            // float4 units
  if (idx < 1572864) {
    float4 v = reinterpret_cast<const float4*>(x)[idx];
    u16x4 o;
    o.x = f2b(v.x); o.y = f2b(v.y); o.z = f2b(v.z); o.w = f2b(v.w);
    reinterpret_cast<u16x4*>(xb)[idx] = o;
  } else {
    int j = idx - 1572864;                             // 0..4718591
    const float* src; int s;
    if (j < 3145728)      { src = wq; s = j; }
    else if (j < 3932160) { src = wk; s = j - 3145728; }
    else                  { src = wv; s = j - 3932160; }
    float4 v = reinterpret_cast<const float4*>(src)[s];
    u16x4 o;
    o.x = f2b(v.x); o.y = f2b(v.y); o.z = f2b(v.z); o.w = f2b(v.w);
    reinterpret_cast<u16x4*>(wqkv)[j] = o;
  }
}

// ---------------- BMT x 192 8-wave NT GEMM, bf16 B (verified round 12) ------
template<int BMT, bool OUT_BF16>
__global__ __launch_bounds__(512, 4)
void k_gemm192(const unsigned short* __restrict__ A,
               const unsigned short* __restrict__ B,
               void* __restrict__ Cout, int N, int K, int KT,
               int nbn, int xcdq) {
  constexpr int AROWS  = BMT / 64;
  constexpr int AFRAG  = BMT / 32;
  constexpr int LDSBUF = BMT * 128 + 24576;
  __shared__ char lds[2 * LDSBUF];
  const int bid = blockIdx.x;
  const int swz = (bid & 7) * xcdq + (bid >> 3);       // bijective: nwg % 8 == 0
  const int bm  = swz / nbn, bn = swz % nbn;
  const int tid = threadIdx.x, lane = tid & 63, wid = tid >> 6;
  const int wm  = wid >> 2, wn = wid & 3;              // 2 x 4
  const int r16 = lane & 15, q4 = lane >> 4;

  const unsigned short* Ag = A + (size_t)(bm * BMT) * K;
  const unsigned short* Bg = B + (size_t)(bn * 192) * K;

  const int srow = tid >> 3;                            // 0..63
  const int scol = ((tid & 7) ^ (srow & 7)) * 8;        // pre-swizzled src col

  f32x4 acc[AFRAG][3] = {};
  s16x8 af[AFRAG][2];

  auto stageA = [&](int c, int r, int t) {
    gld_lds16(Ag + (size_t)(r * 64 + srow) * K + t * 64 + scol,
              lds + c * LDSBUF + r * 8192 + tid * 16);
  };
  auto stageB = [&](int c, int r, int t) {
    gld_lds16(Bg + (size_t)(r * 64 + srow) * K + t * 64 + scol,
              lds + c * LDSBUF + BMT * 128 + r * 8192 + tid * 16);
  };
  auto readA = [&](int c) {
    #pragma unroll
    for (int i = 0; i < AFRAG; ++i) {
      const int arow = wm * (BMT / 2) + i * 16 + r16;
      #pragma unroll
      for (int kk = 0; kk < 2; ++kk)
        af[i][kk] = *(const s16x8*)(lds + c * LDSBUF + arow * 128 +
                                    (((kk * 4 + q4) ^ (arow & 7)) << 4));
    }
  };
  auto readB = [&](s16x8 (&dst)[2], int c, int j) {
    const int brow = wn * 48 + j * 16 + r16;
    #pragma unroll
    for (int kk = 0; kk < 2; ++kk)
      dst[kk] = *(const s16x8*)(lds + c * LDSBUF + BMT * 128 + brow * 128 +
                                (((kk * 4 + q4) ^ (brow & 7)) << 4));
  };

#define MFMA8(BF, J)                                                           \
  __builtin_amdgcn_s_setprio(1);                                               \
  _Pragma("unroll")                                                            \
  for (int i_ = 0; i_ < AFRAG; ++i_) {                                         \
    _Pragma("unroll")                                                          \
    for (int kk_ = 0; kk_ < 2; ++kk_)                                          \
      acc[i_][J] = __builtin_amdgcn_mfma_f32_16x16x32_bf16(                    \
          af[i_][kk_], BF[kk_], acc[i_][J], 0, 0, 0);                          \
  }                                                                            \
  __builtin_amdgcn_s_setprio(0);

  #pragma unroll
  for (int r = 0; r < AROWS; ++r) stageA(0, r, 0);
  stageB(0, 0, 0); stageB(0, 1, 0); stageB(0, 2, 0);
  WAIT_VM(0);
  BAR();

  for (int t = 0; t < KT; ++t) {
    const int c = t & 1;
    const bool hn = (t + 1 < KT);
    s16x8 bf0[2], bf1[2], bf2[2];
    readA(c);
    readB(bf0, c, 0);
    if (hn) {
      #pragma unroll
      for (int r = 0; r < AROWS; ++r) stageA(c ^ 1, r, t + 1);
      stageB(c ^ 1, 0, t + 1); stageB(c ^ 1, 1, t + 1); stageB(c ^ 1, 2, t + 1);
    }
    readB(bf1, c, 1);
    WAIT_LGKM(2); SCHEDB();
    MFMA8(bf0, 0);
    readB(bf2, c, 2);
    WAIT_LGKM(2); SCHEDB();
    MFMA8(bf1, 1);
    WAIT_LGKM(0); SCHEDB();
    MFMA8(bf2, 2);
    if (hn) WAIT_VM(0);
    BAR();
  }
#undef MFMA8

  #pragma unroll
  for (int i = 0; i < AFRAG; ++i) {
    const int row = bm * BMT + wm * (BMT / 2) + i * 16 + q4 * 4;
    #pragma unroll
    for (int j = 0; j < 3; ++j) {
      const int col = bn * 192 + wn * 48 + j * 16 + r16;
      if constexpr (OUT_BF16) {
        unsigned short* C = (unsigned short*)Cout;
        #pragma unroll
        for (int rr = 0; rr < 4; ++rr)
          C[(size_t)(row + rr) * N + col] = f2b(acc[i][j][rr]);
      } else {
        float* C = (float*)Cout;
        #pragma unroll
        for (int rr = 0; rr < 4; ++rr)
          C[(size_t)(row + rr) * N + col] = acc[i][j][rr];
      }
    }
  }
}

// ---------------- merged prep: wo-cvt | ropeK | V-transpose | prefix --------
__global__ __launch_bounds__(256)
void k_prep(const unsigned short* __restrict__ qkv,
            const float* __restrict__ fc, const float* __restrict__ fs,
            const float* __restrict__ kc, const float* __restrict__ vc,
            const float* __restrict__ wo, unsigned short* __restrict__ wo_b,
            unsigned short* __restrict__ Kall,
            unsigned short* __restrict__ VT, const int* __restrict__ ipos) {
  __shared__ unsigned short lds[64][136];
  const int b = blockIdx.x, tid = threadIdx.x;

  if (b < 12288) {                             // ---- wo f32 -> bf16
    int idx = b * 256 + tid;                   // f4 units, 3145728 total
    float4 v = reinterpret_cast<const float4*>(wo)[idx];
    u16x4 o;
    o.x = f2b(v.x); o.y = f2b(v.y); o.z = f2b(v.z); o.w = f2b(v.w);
    reinterpret_cast<u16x4*>(wo_b)[idx] = o;

  } else if (b < 13312) {                      // ---- RoPE K -> Kall
    int idx = (b - 12288) * 256 + tid;
    int t   = idx >> 7;
    int rem = idx & 127;
    int hk  = rem >> 4;
    int c8  = (rem & 15) << 3;
    int sp  = ipos[0];
    s16x8 xv = *(const s16x8*)(qkv + (size_t)t * NQKV_ + HQ_ * HD_ + hk * HD_ + c8);
    float4 ca = *(const float4*)(fc + t * HD_ + c8);
    float4 cb = *(const float4*)(fc + t * HD_ + c8 + 4);
    float4 sa = *(const float4*)(fs + t * HD_ + c8);
    float4 sb = *(const float4*)(fs + t * HD_ + c8 + 4);
    float cc[8] = {ca.x, ca.y, ca.z, ca.w, cb.x, cb.y, cb.z, cb.w};
    float ss[8] = {sa.x, sa.y, sa.z, sa.w, sb.x, sb.y, sb.z, sb.w};
    s16x8 o;
    #pragma unroll
    for (int i = 0; i < 4; ++i) {
      float x0 = b2f((unsigned short)xv[2 * i]);
      float x1 = b2f((unsigned short)xv[2 * i + 1]);
      o[2 * i]     = (short)f2b(x0 * cc[2 * i]     - x1 * ss[2 * i]);
      o[2 * i + 1] = (short)f2b(x1 * cc[2 * i + 1] + x0 * ss[2 * i + 1]);
    }
    *(s16x8*)(Kall + ((size_t)hk * S_ + sp + t) * HD_ + c8) = o;

  } else if (b < 13568) {                      // ---- V transpose -> VT
    int bb = b - 13312;
    int hk = bb >> 5;
    int tt = bb & 31;
    int sp = ipos[0];
    #pragma unroll
    for (int p = 0; p < 4; ++p) {
      int e   = p * 256 + tid;
      int tr  = e >> 4;
      int col = (e & 15) << 3;
      *reinterpret_cast<s16x8*>(&lds[tr][col]) =
          *reinterpret_cast<const s16x8*>(&qkv[(size_t)(tt * 64 + tr) * NQKV_ +
                                               (HQ_ + HKV_) * HD_ + hk * HD_ + col]);
    }
    __syncthreads();
    #pragma unroll
    for (int p = 0; p < 32; ++p) {
      int e = p * 256 + tid;
      int d = e >> 6;
      int t = e & 63;
      VT[((size_t)hk * HD_ + d) * S_ + sp + tt * 64 + t] = lds[t][d];
    }

  } else {                                     // ---- cache prefix (s < sp)
    int sp = ipos[0];
    int total = sp * HKV_ * HD_;
    for (int idx = (b - 13568) * 256 + tid; idx < total; idx += 256 * 256) {
      int s   = idx >> 10;
      int rem = idx & 1023;
      int hk  = rem >> 7;
      int d   = rem & 127;
      Kall[((size_t)hk * S_ + s) * HD_ + d] = f2b(kc[((size_t)s * HKV_ + hk) * HD_ + d]);
      VT[((size_t)hk * HD_ + d) * S_ + s]   = f2b(vc[((size_t)s * HKV_ + hk) * HD_ + d]);
    }
  }
}

// ---------------- flash attention v9: fused RoPE-Q, 1 barrier/tile ----------
// v18 structure with the publish/protect barriers merged: per tile j,
// WAIT_VM(0) [my tile-j loads landed] -> BAR [publish j; all waves done
// reading buf c^1 from tile j-1] -> stage(c^1, j+1) [overwrite safe] ->
// compute tile j from buf c. Hide window unchanged; barriers/tile 2 -> 1.
__global__ __launch_bounds__(256, 2)
void k_attn(const unsigned short* __restrict__ qkv,
            const float* __restrict__ fc, const float* __restrict__ fs,
            const unsigned short* __restrict__ Kall,
            const unsigned short* __restrict__ VT,
            unsigned short* __restrict__ Y,
            const int* __restrict__ ipos) {
  constexpr int QB = 64, KB = 64;
  __shared__ char lds[65536];
  const int bid  = blockIdx.x;
  const int hk   = bid & 7;
  const int j2   = bid >> 3;                  // 0..127
  const int h    = hk * 4 + (j2 & 3);
  const int qt   = 31 - (j2 >> 2);            // LPT: longest first
  const int tid  = threadIdx.x, lane = tid & 63, wave = tid >> 6;
  const int r16  = lane & 15, q4 = lane >> 4;
  const int vx   = r16 & 7;                   // row-XOR for all LDS reads
  const float NEG_INF = -__builtin_inff();
  const float MINIT   = -1.0e30f;

  const int sp = ipos[0];
  const int qbase = qt * QB + wave * 16;
  const unsigned short* Kbase = Kall + (size_t)hk * S_ * HD_;
  const unsigned short* Vbase = VT + (size_t)hk * HD_ * S_;

  // Q fragments straight from qkv + in-register RoPE (pairs are lane-local)
  s16x8 qf[4];
  {
    const int tq = qbase + r16;
    const unsigned short* qp = qkv + (size_t)tq * NQKV_ + h * HD_;
    const float* fcb = fc + tq * HD_;
    const float* fsb = fs + tq * HD_;
    #pragma unroll
    for (int ki = 0; ki < 4; ++ki) {
      const int d0 = ki * 32 + q4 * 8;
      s16x8 xv = *reinterpret_cast<const s16x8*>(qp + d0);
      float4 ca = *(const float4*)(fcb + d0);
      float4 cb = *(const float4*)(fcb + d0 + 4);
      float4 sa = *(const float4*)(fsb + d0);
      float4 sb = *(const float4*)(fsb + d0 + 4);
      float cc[8] = {ca.x, ca.y, ca.z, ca.w, cb.x, cb.y, cb.z, cb.w};
      float ss[8] = {sa.x, sa.y, sa.z, sa.w, sb.x, sb.y, sb.z, sb.w};
      #pragma unroll
      for (int i = 0; i < 4; ++i) {
        float x0 = b2f((unsigned short)xv[2 * i]);
        float x1 = b2f((unsigned short)xv[2 * i + 1]);
        qf[ki][2 * i]     = (short)f2b(x0 * cc[2 * i]     - x1 * ss[2 * i]);
        qf[ki][2 * i + 1] = (short)f2b(x1 * cc[2 * i + 1] + x0 * ss[2 * i + 1]);
      }
    }
  }
  SCHEDB(); WAIT_VM(0); SCHEDB();             // drain Q/freq loads: exact ledger

  auto stage = [&](int c, int jt) {           // 8 gld_lds per thread
    #pragma unroll
    for (int p = 0; p < 4; ++p) {
      int e  = p * 256 + tid;
      int kr = e >> 4;
      int ks = (e & 15) ^ (kr & 7);
      gld_lds16(Kbase + (size_t)(jt * KB + kr) * HD_ + ks * 8,
                lds + c * 16384 + e * 16);
    }
    #pragma unroll
    for (int p = 0; p < 4; ++p) {
      int e  = p * 256 + tid;
      int vd = e >> 3;
      int vs = (e & 7) ^ (vd & 7);
      gld_lds16(Vbase + (size_t)vd * S_ + jt * KB + vs * 8,
                lds + 32768 + c * 16384 + e * 16);
    }
  };

  f32x4 o[8] = {};
  float m = MINIT, l = 0.f;
  const int qpos = sp + qbase + r16;
  const int qpos_wave_max = sp + qbase + 15;
  int jmax = (sp + qt * QB + QB - 1) >> 6;
  if (jmax > S_ / KB - 1) jmax = S_ / KB - 1;
  const float scale2 = 0.12751744416312068f;  // 1/sqrt(128) * log2(e)

  stage(0, 0);                                // prologue: tile 0 in flight (8)

  for (int j = 0; j <= jmax; ++j) {
    const int c = j & 1;
    WAIT_VM(0);                               // my tile-j loads landed
    BAR();                                    // publish j; buf c^1 readers done
    if (j < jmax) stage(c ^ 1, j + 1);        // overwrite c^1: safe post-BAR

    const bool active = (j * KB <= qpos_wave_max);
    if (active) {
      const char* kb = lds + c * 16384;
      const char* vb = lds + 32768 + c * 16384;
      f32x4 sfr[4];
      __builtin_amdgcn_s_setprio(1);
      #pragma unroll
      for (int fn = 0; fn < 4; ++fn) {
        sfr[fn] = f32x4{0.f, 0.f, 0.f, 0.f};
        #pragma unroll
        for (int ki = 0; ki < 4; ++ki) {
          s16x8 kf = *(const s16x8*)(kb + (fn * 16 + r16) * 256 +
                                     (((ki * 4 + q4) ^ vx) << 4));
          sfr[fn] = __builtin_amdgcn_mfma_f32_16x16x32_bf16(kf, qf[ki], sfr[fn], 0, 0, 0);
        }
      }
      __builtin_amdgcn_s_setprio(0);
      float p[16];
      const bool needMask = (j * KB + KB - 1) > (sp + qbase);   // wave-uniform
      if (needMask) {
        const int kbp = j * KB + q4 * 4;
        #pragma unroll
        for (int fn = 0; fn < 4; ++fn)
          #pragma unroll
          for (int r = 0; r < 4; ++r)
            p[fn * 4 + r] = (kbp + fn * 16 + r <= qpos) ? sfr[fn][r] * scale2 : NEG_INF;
      } else {
        #pragma unroll
        for (int fn = 0; fn < 4; ++fn)
          #pragma unroll
          for (int r = 0; r < 4; ++r)
            p[fn * 4 + r] = sfr[fn][r] * scale2;
      }
      float t0 = fmaxf(p[0], p[1]),  t1 = fmaxf(p[2], p[3]);
      float t2 = fmaxf(p[4], p[5]),  t3 = fmaxf(p[6], p[7]);
      float t4 = fmaxf(p[8], p[9]),  t5 = fmaxf(p[10], p[11]);
      float t6 = fmaxf(p[12], p[13]), t7 = fmaxf(p[14], p[15]);
      float pmax = fmaxf(fmaxf(fmaxf(t0, t1), fmaxf(t2, t3)),
                         fmaxf(fmaxf(t4, t5), fmaxf(t6, t7)));
      pmax = fmaxf(pmax, __shfl_xor(pmax, 16));
      pmax = fmaxf(pmax, __shfl_xor(pmax, 32));
      if (!__all(pmax <= m + 8.0f)) {                 // defer-max (log2 units)
        float mn = fmaxf(m, pmax);
        float alpha = exp2a(m - mn);
        m = mn; l *= alpha;
        #pragma unroll
        for (int r = 0; r < 4; ++r) {
          float aq = __shfl(alpha, q4 * 4 + r);
          #pragma unroll
          for (int db = 0; db < 8; ++db) o[db][r] *= aq;
        }
      }
      float rs = 0.f;
      #pragma unroll
      for (int i = 0; i < 16; ++i) { p[i] = exp2a(p[i] - m); rs += p[i]; }
      rs += __shfl_xor(rs, 16); rs += __shfl_xor(rs, 32);
      l += rs;
      s16x8 pf[2];
      #pragma unroll
      for (int w = 0; w < 2; ++w)
        #pragma unroll
        for (int i = 0; i < 8; ++i)
          pf[w][i] = (short)f2b(p[w * 8 + i]);
      const int voff = (q4 & 1) * 8;
      const int sbase = q4 >> 1;
      __builtin_amdgcn_s_setprio(1);
      #pragma unroll
      for (int w = 0; w < 2; ++w) {
        #pragma unroll
        for (int db = 0; db < 8; ++db) {
          const char* vr = vb + (db * 16 + r16) * 128 + voff;
          s16x4 va  = *(const s16x4*)(vr + (((w * 4 + sbase) ^ vx) << 4));
          s16x4 vb2 = *(const s16x4*)(vr + (((w * 4 + 2 + sbase) ^ vx) << 4));
          s16x8 vf = __builtin_shufflevector(va, vb2, 0, 1, 2, 3, 4, 5, 6, 7);
          o[db] = __builtin_amdgcn_mfma_f32_16x16x32_bf16(pf[w], vf, o[db], 0, 0, 0);
        }
      }
      __builtin_amdgcn_s_setprio(0);
    }
    // single barrier per tile: next iteration's BAR protects buf c
  }

  float rcpl = 1.0f / l;
  float rlq[4];
  #pragma unroll
  for (int r = 0; r < 4; ++r) rlq[r] = __shfl(rcpl, q4 * 4 + r);
  #pragma unroll
  for (int db = 0; db < 8; ++db)
    #pragma unroll
    for (int r = 0; r < 4; ++r) {
      int t = qt * QB + wave * 16 + q4 * 4 + r;
      int d = db * 16 + r16;
      Y[(size_t)t * (HQ_ * HD_) + h * HD_ + d] = f2b(o[db][r] * rlq[r]);
    }
}

// ---------------------------------------------------------------------------
extern "C" void kernel_launch(void* const* d_in, const int* in_sizes, int n_in,
                              void* d_out, int out_size, void* d_ws, size_t ws_size,
                              hipStream_t stream) {
  const float* x  = (const float*)d_in[0];
  const float* wq = (const float*)d_in[1];
  const float* wk = (const float*)d_in[2];
  const float* wv = (const float*)d_in[3];
  const float* wo = (const float*)d_in[4];
  const float* fc = (const float*)d_in[5];
  const float* fs = (const float*)d_in[6];
  const float* kc = (const float*)d_in[7];
  const float* vc = (const float*)d_in[8];
  const int* ipos = (const int*)d_in[9];

  char* ws = (char*)d_ws;
  unsigned short* xb   = (unsigned short*)(ws);                 // [0, 12.58 MB)
  unsigned short* wqkv = (unsigned short*)(ws + 12582912);      // [12.58, 50.33)
  unsigned short* qkv  = (unsigned short*)(ws + 50331648);      // [50.33, 75.50)
  unsigned short* y    = (unsigned short*)(ws + 75497472);      // [75.50, 92.27) no alias
  unsigned short* Kall = (unsigned short*)(ws + 92274688);      // [92.27, 100.66)
  unsigned short* VT   = (unsigned short*)(ws + 100663296);     // [100.66, 109.05)
  unsigned short* wo_b = (unsigned short*)(ws);                 // reuse region 0 after QKV GEMM

  // converts: x + wq + wk + wv, one launch
  k_cvtA<<<24576, 256, 0, stream>>>(x, wq, wk, wv, xb, wqkv);

  // fused QKV projection: qkv[2048][6144] = xb @ wqkv^T (512 blocks = 2/CU)
  k_gemm192<128, true><<<512, 512, 0, stream>>>(xb, wqkv, qkv, NQKV_, DIM_, 48, 32, 64);

  // merged wo-cvt / RoPE-K / V-transpose / prefix (region 0 dead now)
  k_prep<<<13824, 256, 0, stream>>>(qkv, fc, fs, kc, vc, wo, wo_b, Kall, VT, ipos);

  // attention -> y: v9 single-barrier, K/V dbuf, 1024 blocks
  k_attn<<<1024, 256, 0, stream>>>(qkv, fc, fs, Kall, VT, y, ipos);

  // output projection: out[2048][3072] = y @ wo_b^T, f32 direct (BM=64, 2/CU)
  k_gemm192<64, false><<<512, 512, 0, stream>>>(y, wo_b, d_out, DIM_, HQ_ * HD_, 64, 16, 64);
}